// Round 3
// baseline (18.405 us; speedup 1.0000x reference)
//
#include <hip/hip_runtime.h>

// QuantumKernelAttention, rank-16 factorization + MFMA epilogue (R6):
//   K[b,i,j] = prod_k ( c_ik c_jk + s_ik s_jk ) = sum_t F[i,t] F[j,t]  (rank 16)
//   F pre-scaled by sqrt(log2 e) so Gram = K*log2e and e = exp2(|d|) is one
//   v_exp_f32 with free |.| input modifier. E packed to f16 in-register
//   (cvt_pkrtz + permlane32_swap) and fed to a second 32x32x16 MFMA against
//   [x | 1]^T: D[:,0..3] = sum e*x, D[:,4] = sum e (softmax denominator).
// R6 vs R5: distance-2 LDS prefetch (af/xf read ~2 tiles ahead; ds_read ~120cy
// latency now hidden under the exp burst instead of exposed before each MFMA);
// dependent-chain reorder (exps consume d BEFORE next Gram writes dn -> peak
// VGPR liveness drops ~16-24, safely under the 128 cap of launch_bounds(512,4));
// full unroll of the 8-tile loop (SSA, static indices, cross-tile scheduling).

typedef _Float16 f16x8 __attribute__((ext_vector_type(8)));
typedef float    f32x16 __attribute__((ext_vector_type(16)));
typedef unsigned int u32x4 __attribute__((ext_vector_type(4)));

#define SQ 1024
#define NTHREADS 512   // 8 waves: 2 row-tiles x 4 j-quarters
#define ROWS 64        // output rows per block

__device__ __forceinline__ unsigned pk16(float a, float b) {
    auto p = __builtin_amdgcn_cvt_pkrtz(a, b);   // 2 x f32 -> packed f16x2
    return __builtin_bit_cast(unsigned, p);
}

#if __has_builtin(__builtin_amdgcn_permlane32_swap)
__device__ __forceinline__ void pl32swap(unsigned &a, unsigned &b) {
    auto r = __builtin_amdgcn_permlane32_swap(a, b, false, false);
    a = r[0]; b = r[1];
}
#else
__device__ __forceinline__ void pl32swap(unsigned &a, unsigned &b) {
    asm("v_permlane32_swap_b32 %0, %1" : "+v"(a), "+v"(b));
}
#endif

// e = exp(|K|) = exp2(|K * log2e|); the Gram already carries the log2e factor.
__device__ __forceinline__ float ex2(float v) {
    return __builtin_amdgcn_exp2f(fabsf(v));
}

__global__ __launch_bounds__(NTHREADS, 4)
void qka_kernel(const float* __restrict__ x, float* __restrict__ out) {
    // F factors (pre-scaled by sqrt(log2e)), k-halves split; rows XOR-swizzled
    // (j ^ ((j>>3)&7)) so a wave's ds_read_b128 of 32 rows is conflict-minimal.
    __shared__ f16x8 lds_F0[SQ];        // 16 KB  F[j][k=0..7]
    __shared__ f16x8 lds_F1[SQ];        // 16 KB  F[j][k=8..15]
    // X^T extended, f16: rows 0..3 = x components, row 4 = ones (denominator).
    __shared__ f16x8 lds_XT[5 * 129];   // ~10.1 KB, pitch 129 f16x8

    const int bid   = blockIdx.x;
    const int b     = bid >> 4;          // 16 row-tiles (of 64) per batch
    const int Ibase = (bid & 15) * ROWS;
    const int tid   = threadIdx.x;

    const float4* xb  = (const float4*)(x + (size_t)b * SQ * 4);
    _Float16*     xtp = (_Float16*)lds_XT;

    // ---- stage: F (f16, swizzled, scaled) and X^T+ones (f16), whole batch ----
    #pragma unroll
    for (int k = 0; k < SQ / NTHREADS; ++k) {
        int j = tid + k * NTHREADS;
        float4 v = xb[j];
        const float SC = 1.2011224087f;  // sqrt(log2 e)
        float c0 = __cosf(0.5f * v.x), s0 = __sinf(0.5f * v.x);
        float c1 = __cosf(0.5f * v.y), s1 = __sinf(0.5f * v.y);
        float c2 = __cosf(0.5f * v.z), s2 = __sinf(0.5f * v.z);
        float c3 = SC * __cosf(0.5f * v.w), s3 = SC * __sinf(0.5f * v.w);
        float m0 = c0 * c1, m1 = s0 * c1, m2 = c0 * s1, m3 = s0 * s1;
        float n0 = m0 * c2, n1 = m1 * c2, n2 = m2 * c2, n3 = m3 * c2;
        float n4 = m0 * s2, n5 = m1 * s2, n6 = m2 * s2, n7 = m3 * s2;
        f16x8 p0, p1;
        p0[0] = (_Float16)(n0 * c3); p0[1] = (_Float16)(n1 * c3);
        p0[2] = (_Float16)(n2 * c3); p0[3] = (_Float16)(n3 * c3);
        p0[4] = (_Float16)(n4 * c3); p0[5] = (_Float16)(n5 * c3);
        p0[6] = (_Float16)(n6 * c3); p0[7] = (_Float16)(n7 * c3);
        p1[0] = (_Float16)(n0 * s3); p1[1] = (_Float16)(n1 * s3);
        p1[2] = (_Float16)(n2 * s3); p1[3] = (_Float16)(n3 * s3);
        p1[4] = (_Float16)(n4 * s3); p1[5] = (_Float16)(n5 * s3);
        p1[6] = (_Float16)(n6 * s3); p1[7] = (_Float16)(n7 * s3);
        int sj = j ^ ((j >> 3) & 7);
        lds_F0[sj] = p0;
        lds_F1[sj] = p1;
        xtp[0 * 1032 + j] = (_Float16)v.x;
        xtp[1 * 1032 + j] = (_Float16)v.y;
        xtp[2 * 1032 + j] = (_Float16)v.z;
        xtp[3 * 1032 + j] = (_Float16)v.w;
        xtp[4 * 1032 + j] = (_Float16)1.0f;
    }
    __syncthreads();

    // ---- main: wave = (row-tile rt, j-quarter q); 8 tiles of 32 j each ----
    const int wid  = tid >> 6;
    const int q    = wid & 3;            // j-quarter: j in [256q, 256q+256)
    const int rt   = wid >> 2;           // row-tile within block (0/1)
    const int lane = tid & 63;
    const int h    = lane >> 5;          // k-half selector
    const int ln   = lane & 31;

    const f16x8* Fh = h ? lds_F1 : lds_F0;
    int ib = Ibase + rt * 32 + ln; ib ^= (ib >> 3) & 7;
    const f16x8 bfrag = Fh[ib];          // B: F[I-tile] rows (col n = i)

    // PV B-frag: lane col n reads X^T row min(n,4); cols >=5 never read back.
    const int rowsel = (ln < 4) ? ln : 4;
    const int xbase  = rowsel * 129 + q * 32 + h;   // f16x8 index

    f32x16 oacc0 = (f32x16)(0.0f);       // e-rows k=j' 0..15
    f32x16 oacc1 = (f32x16)(0.0f);       // e-rows k=j' 16..31

    // Distance-2 prefetch pipeline: LDS reads for tile t issued at t-2.
    f16x8 af[8], xfa[8], xfb[8];
    {
        int j0 = q * 256 + ln;
        af[0]  = Fh[j0 ^ ((j0 >> 3) & 7)];
        int j1 = q * 256 + 32 + ln;
        af[1]  = Fh[j1 ^ ((j1 >> 3) & 7)];
        xfa[0] = lds_XT[xbase];     xfb[0] = lds_XT[xbase + 2];
        xfa[1] = lds_XT[xbase + 4]; xfb[1] = lds_XT[xbase + 6];
    }
    f32x16 d = __builtin_amdgcn_mfma_f32_32x32x16_f16(
        af[0], bfrag, (f32x16)(0.0f), 0, 0, 0);

    #pragma unroll
    for (int t = 0; t < 8; ++t) {
        // prefetch LDS operands for tile t+2 (latency hides under exp burst)
        if (t < 6) {
            int jn = q * 256 + (t + 2) * 32 + ln;
            af[t + 2]  = Fh[jn ^ ((jn >> 3) & 7)];
            xfa[t + 2] = lds_XT[xbase + (t + 2) * 4];
            xfb[t + 2] = lds_XT[xbase + (t + 2) * 4 + 2];
        }
        // d[r] = log2e*K[j', i], j' = (r&3)+8(r>>2)+4h; e = exp2(|d|) in [1,e].
        // Exps consume d FIRST (d dies here) -> next Gram reuses its registers.
        unsigned q0 = pk16(ex2(d[0]),  ex2(d[1]));
        unsigned q1 = pk16(ex2(d[2]),  ex2(d[3]));
        unsigned q2 = pk16(ex2(d[4]),  ex2(d[5]));
        unsigned q3 = pk16(ex2(d[6]),  ex2(d[7]));
        unsigned q4 = pk16(ex2(d[8]),  ex2(d[9]));
        unsigned q5 = pk16(ex2(d[10]), ex2(d[11]));
        unsigned q6 = pk16(ex2(d[12]), ex2(d[13]));
        unsigned q7 = pk16(ex2(d[14]), ex2(d[15]));
        f32x16 dn;
        if (t < 7)   // Gram for t+1; ~40cy latency hides under pack + PV below
            dn = __builtin_amdgcn_mfma_f32_32x32x16_f16(
                af[t + 1], bfrag, (f32x16)(0.0f), 0, 0, 0);
        pl32swap(q0, q2); pl32swap(q1, q3);   // frag0 dwords 0..3 (k = 0..15)
        pl32swap(q4, q6); pl32swap(q5, q7);   // frag1 dwords 0..3 (k = 16..31)
        u32x4 w0 = {q0, q1, q2, q3};
        u32x4 w1 = {q4, q5, q6, q7};
        f16x8 ef0 = __builtin_bit_cast(f16x8, w0);
        f16x8 ef1 = __builtin_bit_cast(f16x8, w1);
        oacc0 = __builtin_amdgcn_mfma_f32_32x32x16_f16(ef0, xfa[t], oacc0, 0, 0, 0);
        oacc1 = __builtin_amdgcn_mfma_f32_32x32x16_f16(ef1, xfb[t], oacc1, 0, 0, 0);
        if (t < 7) d = dn;
    }

    // ---- cross-wave combine: partials in LDS (alias onto lds_F0, now dead) ----
    __syncthreads();                     // all waves done reading F / XT
    float* ps = (float*)lds_F0;          // [q=4][64 rows][8 cols f32] = 8 KB
    if (ln < 5) {                        // cols 0..4 valid, both halves
        #pragma unroll
        for (int r = 0; r < 16; ++r) {
            int m = (r & 3) + 8 * (r >> 2) + 4 * h;   // row within 32-tile
            ps[(q * 64 + rt * 32 + m) * 8 + ln] = oacc0[r] + oacc1[r];
        }
    }
    __syncthreads();

    if (tid < ROWS) {
        float nx = 0.f, ny = 0.f, nz = 0.f, nw = 0.f, den = 0.f;
        #pragma unroll
        for (int qq = 0; qq < 4; ++qq) {
            const float* p = &ps[(qq * 64 + tid) * 8];
            nx += p[0]; ny += p[1]; nz += p[2]; nw += p[3]; den += p[4];
        }
        float inv = 1.0f / den;
        ((float4*)out)[(size_t)b * SQ + Ibase + tid] =
            make_float4(nx * inv, ny * inv, nz * inv, nw * inv);
    }
}

extern "C" void kernel_launch(void* const* d_in, const int* in_sizes, int n_in,
                              void* d_out, int out_size, void* d_ws, size_t ws_size,
                              hipStream_t stream) {
    const float* x = (const float*)d_in[0];
    float* out = (float*)d_out;
    dim3 grid(32 * (SQ / ROWS));   // 512 blocks
    dim3 block(NTHREADS);
    qka_kernel<<<grid, block, 0, stream>>>(x, out);
}

// Round 4
// 11.989 us; speedup vs baseline: 1.5351x; 1.5351x over previous
//
#include <hip/hip_runtime.h>

// QuantumKernelAttention, rank-16 factorization + MFMA epilogue (R7):
//   K[b,i,j] = prod_k ( c_ik c_jk + s_ik s_jk ) = sum_t F[i,t] F[j,t]  (rank 16)
//   F pre-scaled by sqrt(log2 e) so Gram = K*log2e and e = exp2(|d|) is one
//   v_exp_f32 with free |.| input modifier. E packed to f16 in-register
//   (cvt_pkrtz + permlane32_swap) and fed to a second 32x32x16 MFMA against
//   [x | 1]^T: D[:,0..3] = sum e*x, D[:,4] = sum e (softmax denominator).
// R7 vs R5: loop-body reorder ONLY (R6's distance-2 array pipeline spilled:
// +96 VGPR past the 128 cap of launch_bounds(512,4) -> 18.4us; reverted).
// New order: issue ds_read afn/xf FIRST, then the 16-exp trans burst (~128cy,
// depends only on prev tile's d) covers the ~120cy ds_read latency, then
// Gram(t+1) finds lgkmcnt satisfied. Peak liveness ~100 VGPR (d dies into
// the packs before dn is written). No other changes from R5.

typedef _Float16 f16x8 __attribute__((ext_vector_type(8)));
typedef float    f32x16 __attribute__((ext_vector_type(16)));
typedef unsigned int u32x4 __attribute__((ext_vector_type(4)));

#define SQ 1024
#define NTHREADS 512   // 8 waves: 2 row-tiles x 4 j-quarters
#define ROWS 64        // output rows per block

__device__ __forceinline__ unsigned pk16(float a, float b) {
    auto p = __builtin_amdgcn_cvt_pkrtz(a, b);   // 2 x f32 -> packed f16x2
    return __builtin_bit_cast(unsigned, p);
}

#if __has_builtin(__builtin_amdgcn_permlane32_swap)
__device__ __forceinline__ void pl32swap(unsigned &a, unsigned &b) {
    auto r = __builtin_amdgcn_permlane32_swap(a, b, false, false);
    a = r[0]; b = r[1];
}
#else
__device__ __forceinline__ void pl32swap(unsigned &a, unsigned &b) {
    asm("v_permlane32_swap_b32 %0, %1" : "+v"(a), "+v"(b));
}
#endif

// e = exp(|K|) = exp2(|K * log2e|); the Gram already carries the log2e factor.
__device__ __forceinline__ float ex2(float v) {
    return __builtin_amdgcn_exp2f(fabsf(v));
}

__global__ __launch_bounds__(NTHREADS, 4)
void qka_kernel(const float* __restrict__ x, float* __restrict__ out) {
    // F factors (pre-scaled by sqrt(log2e)), k-halves split; rows XOR-swizzled
    // (j ^ ((j>>3)&7)) so a wave's ds_read_b128 of 32 rows is conflict-minimal.
    __shared__ f16x8 lds_F0[SQ];        // 16 KB  F[j][k=0..7]
    __shared__ f16x8 lds_F1[SQ];        // 16 KB  F[j][k=8..15]
    // X^T extended, f16: rows 0..3 = x components, row 4 = ones (denominator).
    __shared__ f16x8 lds_XT[5 * 129];   // ~10.1 KB, pitch 129 f16x8

    const int bid   = blockIdx.x;
    const int b     = bid >> 4;          // 16 row-tiles (of 64) per batch
    const int Ibase = (bid & 15) * ROWS;
    const int tid   = threadIdx.x;

    const float4* xb  = (const float4*)(x + (size_t)b * SQ * 4);
    _Float16*     xtp = (_Float16*)lds_XT;

    // ---- stage: F (f16, swizzled, scaled) and X^T+ones (f16), whole batch ----
    #pragma unroll
    for (int k = 0; k < SQ / NTHREADS; ++k) {
        int j = tid + k * NTHREADS;
        float4 v = xb[j];
        const float SC = 1.2011224087f;  // sqrt(log2 e)
        float c0 = __cosf(0.5f * v.x), s0 = __sinf(0.5f * v.x);
        float c1 = __cosf(0.5f * v.y), s1 = __sinf(0.5f * v.y);
        float c2 = __cosf(0.5f * v.z), s2 = __sinf(0.5f * v.z);
        float c3 = SC * __cosf(0.5f * v.w), s3 = SC * __sinf(0.5f * v.w);
        float m0 = c0 * c1, m1 = s0 * c1, m2 = c0 * s1, m3 = s0 * s1;
        float n0 = m0 * c2, n1 = m1 * c2, n2 = m2 * c2, n3 = m3 * c2;
        float n4 = m0 * s2, n5 = m1 * s2, n6 = m2 * s2, n7 = m3 * s2;
        f16x8 p0, p1;
        p0[0] = (_Float16)(n0 * c3); p0[1] = (_Float16)(n1 * c3);
        p0[2] = (_Float16)(n2 * c3); p0[3] = (_Float16)(n3 * c3);
        p0[4] = (_Float16)(n4 * c3); p0[5] = (_Float16)(n5 * c3);
        p0[6] = (_Float16)(n6 * c3); p0[7] = (_Float16)(n7 * c3);
        p1[0] = (_Float16)(n0 * s3); p1[1] = (_Float16)(n1 * s3);
        p1[2] = (_Float16)(n2 * s3); p1[3] = (_Float16)(n3 * s3);
        p1[4] = (_Float16)(n4 * s3); p1[5] = (_Float16)(n5 * s3);
        p1[6] = (_Float16)(n6 * s3); p1[7] = (_Float16)(n7 * s3);
        int sj = j ^ ((j >> 3) & 7);
        lds_F0[sj] = p0;
        lds_F1[sj] = p1;
        xtp[0 * 1032 + j] = (_Float16)v.x;
        xtp[1 * 1032 + j] = (_Float16)v.y;
        xtp[2 * 1032 + j] = (_Float16)v.z;
        xtp[3 * 1032 + j] = (_Float16)v.w;
        xtp[4 * 1032 + j] = (_Float16)1.0f;
    }
    __syncthreads();

    // ---- main: wave = (row-tile rt, j-quarter q); 8 tiles of 32 j each ----
    const int wid  = tid >> 6;
    const int q    = wid & 3;            // j-quarter: j in [256q, 256q+256)
    const int rt   = wid >> 2;           // row-tile within block (0/1)
    const int lane = tid & 63;
    const int h    = lane >> 5;          // k-half selector
    const int ln   = lane & 31;

    const f16x8* Fh = h ? lds_F1 : lds_F0;
    int ib = Ibase + rt * 32 + ln; ib ^= (ib >> 3) & 7;
    const f16x8 bfrag = Fh[ib];          // B: F[I-tile] rows (col n = i)

    // PV B-frag: lane col n reads X^T row min(n,4); cols >=5 never read back.
    const int rowsel = (ln < 4) ? ln : 4;
    const int xbase  = rowsel * 129 + q * 32 + h;   // f16x8 index

    f32x16 oacc0 = (f32x16)(0.0f);       // e-rows k=j' 0..15
    f32x16 oacc1 = (f32x16)(0.0f);       // e-rows k=j' 16..31

    // Gram for tile 0, pipelined one tile ahead of the exp/PV stage.
    int ja0 = q * 256 + ln;
    f16x8 af0 = Fh[ja0 ^ ((ja0 >> 3) & 7)];
    f32x16 d = __builtin_amdgcn_mfma_f32_32x32x16_f16(
        af0, bfrag, (f32x16)(0.0f), 0, 0, 0);

    #pragma unroll 2
    for (int t = 0; t < 8; ++t) {
        // Issue ALL this iteration's LDS reads first: next tile's A-fragment
        // and this tile's X fragments. Their ~120cy latency is covered by the
        // 16-exp trans burst below (which depends only on d from tile t).
        f16x8 afn;
        if (t < 7) {
            int jn = q * 256 + (t + 1) * 32 + ln;
            afn = Fh[jn ^ ((jn >> 3) & 7)];
        }
        f16x8 xf0 = lds_XT[xbase + t * 4];        // X rows [jb, jb+16)
        f16x8 xf1 = lds_XT[xbase + t * 4 + 2];    // X rows [jb+16, jb+32)
        // d[r] = log2e*K[j', i], j' = (r&3)+8(r>>2)+4h; e = exp2(|d|) in [1,e].
        unsigned q0 = pk16(ex2(d[0]),  ex2(d[1]));
        unsigned q1 = pk16(ex2(d[2]),  ex2(d[3]));
        unsigned q2 = pk16(ex2(d[4]),  ex2(d[5]));
        unsigned q3 = pk16(ex2(d[6]),  ex2(d[7]));
        unsigned q4 = pk16(ex2(d[8]),  ex2(d[9]));
        unsigned q5 = pk16(ex2(d[10]), ex2(d[11]));
        unsigned q6 = pk16(ex2(d[12]), ex2(d[13]));
        unsigned q7 = pk16(ex2(d[14]), ex2(d[15]));
        // Gram for tile t+1: lgkmcnt for afn satisfied during the exp burst;
        // d is dead (consumed above) so dn can reuse its registers.
        f32x16 dn;
        if (t < 7)
            dn = __builtin_amdgcn_mfma_f32_32x32x16_f16(
                afn, bfrag, (f32x16)(0.0f), 0, 0, 0);
        pl32swap(q0, q2); pl32swap(q1, q3);   // frag0 dwords 0..3 (k = 0..15)
        pl32swap(q4, q6); pl32swap(q5, q7);   // frag1 dwords 0..3 (k = 16..31)
        u32x4 w0 = {q0, q1, q2, q3};
        u32x4 w1 = {q4, q5, q6, q7};
        f16x8 ef0 = __builtin_bit_cast(f16x8, w0);
        f16x8 ef1 = __builtin_bit_cast(f16x8, w1);
        oacc0 = __builtin_amdgcn_mfma_f32_32x32x16_f16(ef0, xf0, oacc0, 0, 0, 0);
        oacc1 = __builtin_amdgcn_mfma_f32_32x32x16_f16(ef1, xf1, oacc1, 0, 0, 0);
        if (t < 7) d = dn;
    }

    // ---- cross-wave combine: partials in LDS (alias onto lds_F0, now dead) ----
    __syncthreads();                     // all waves done reading F / XT
    float* ps = (float*)lds_F0;          // [q=4][64 rows][8 cols f32] = 8 KB
    if (ln < 5) {                        // cols 0..4 valid, both halves
        #pragma unroll
        for (int r = 0; r < 16; ++r) {
            int m = (r & 3) + 8 * (r >> 2) + 4 * h;   // row within 32-tile
            ps[(q * 64 + rt * 32 + m) * 8 + ln] = oacc0[r] + oacc1[r];
        }
    }
    __syncthreads();

    if (tid < ROWS) {
        float nx = 0.f, ny = 0.f, nz = 0.f, nw = 0.f, den = 0.f;
        #pragma unroll
        for (int qq = 0; qq < 4; ++qq) {
            const float* p = &ps[(qq * 64 + tid) * 8];
            nx += p[0]; ny += p[1]; nz += p[2]; nw += p[3]; den += p[4];
        }
        float inv = 1.0f / den;
        ((float4*)out)[(size_t)b * SQ + Ibase + tid] =
            make_float4(nx * inv, ny * inv, nz * inv, nw * inv);
    }
}

extern "C" void kernel_launch(void* const* d_in, const int* in_sizes, int n_in,
                              void* d_out, int out_size, void* d_ws, size_t ws_size,
                              hipStream_t stream) {
    const float* x = (const float*)d_in[0];
    float* out = (float*)d_out;
    dim3 grid(32 * (SQ / ROWS));   // 512 blocks
    dim3 block(NTHREADS);
    qka_kernel<<<grid, block, 0, stream>>>(x, out);
}